// Round 15
// baseline (93.412 us; speedup 1.0000x reference)
//
#include <hip/hip_runtime.h>
#include <stdint.h>

#define B_   4
#define S_   2048
#define IN_  512
#define HID_ 512
#define NH_  8
#define HD_  64
#define M_   (B_*S_)   // 8192
#define CF_  0.18033688011112042f   // log2(e)/8, folded into Wq/bq

typedef __attribute__((ext_vector_type(8)))  short  short8;
typedef __attribute__((ext_vector_type(4)))  short  short4v;
typedef __attribute__((ext_vector_type(4)))  float  f32x4;
typedef __attribute__((ext_vector_type(16))) float  f32x16;
typedef __attribute__((ext_vector_type(8)))  __bf16 bf16x8;
typedef __attribute__((ext_vector_type(2)))  __bf16 bf16x2;
typedef __attribute__((ext_vector_type(4)))  unsigned int u32x4;
typedef __attribute__((ext_vector_type(2)))  unsigned int u32x2;

// fp32 -> bf16 bits, round-to-nearest-even
__device__ __forceinline__ unsigned short f2bf(float f) {
  union { float f; unsigned u; } v; v.f = f;
  unsigned r = (v.u + 0x7fffu + ((v.u >> 16) & 1u)) >> 16;
  return (unsigned short)r;
}

// pack 2 f32 -> u32 of 2 bf16 (v_cvt_pk_bf16_f32)
__device__ __forceinline__ unsigned int packbf(float a, float b) {
  bf16x2 t; t[0] = (__bf16)a; t[1] = (__bf16)b;
  return __builtin_bit_cast(unsigned int, t);
}

// lane-half swap. r[0] = lanes<32: a(own) | lanes>=32: b(partner)
//                 r[1] = lanes<32: a(partner) | lanes>=32: b(own)
__device__ __forceinline__ u32x2 pl32swap(unsigned int a, unsigned int b) {
  return __builtin_amdgcn_permlane32_swap(a, b, false, false);
}

__device__ __forceinline__ f32x4 mfma_bf16(short8 a, short8 b, f32x4 c) {
  return __builtin_amdgcn_mfma_f32_16x16x32_bf16(
      __builtin_bit_cast(bf16x8, a), __builtin_bit_cast(bf16x8, b), c, 0, 0, 0);
}

__device__ __forceinline__ f32x16 mfma32(short8 a, short8 b, f32x16 c) {
  return __builtin_amdgcn_mfma_f32_32x32x16_bf16(
      __builtin_bit_cast(bf16x8, a), __builtin_bit_cast(bf16x8, b), c, 0, 0, 0);
}

// async global->LDS, 16B per lane; dst wave-uniform base (+lane*16 implicit)
__device__ __forceinline__ void gload_lds16(const void* g, void* l) {
  __builtin_amdgcn_global_load_lds(
      (__attribute__((address_space(1))) void*)g,
      (__attribute__((address_space(3))) void*)l, 16, 0, 0);
}

// ---------------- kernel 1: fused prep ----------------
// blocks [0,2048): x fp32 -> xb bf16.  blocks [2048,3072): W transpose+convert.
// Wq is pre-scaled by CF_ (log2e/8) so attention scores arrive in exp2 units.
__global__ __launch_bounds__(256) void sa_prep(const float* __restrict__ x,
                                               short* __restrict__ xb,
                                               const float* __restrict__ Wq,
                                               const float* __restrict__ Wk,
                                               const float* __restrict__ Wv,
                                               const float* __restrict__ Wo,
                                               short* __restrict__ Wt) {
  __shared__ float tile[32][33];
  const int bid = blockIdx.x, tid = threadIdx.x;
  if (bid < 2048) {
    int i = (bid * 256 + tid) * 8;
    const float4* p = (const float4*)&x[i];
    float4 a = p[0], b2 = p[1];
    short8 r;
    r[0] = (short)f2bf(a.x);  r[1] = (short)f2bf(a.y);
    r[2] = (short)f2bf(a.z);  r[3] = (short)f2bf(a.w);
    r[4] = (short)f2bf(b2.x); r[5] = (short)f2bf(b2.y);
    r[6] = (short)f2bf(b2.z); r[7] = (short)f2bf(b2.w);
    *(short8*)&xb[i] = r;
  } else {
    const int wb = bid - 2048;
    const int z = wb >> 8, rem = wb & 255;
    const float* src = (z == 0) ? Wq : (z == 1) ? Wk : (z == 2) ? Wv : Wo;
    const float wsc = (z == 0) ? CF_ : 1.0f;
    const int k0 = (rem >> 4) * 32, n0 = (rem & 15) * 32;
    const int tx = tid & 31, ty = tid >> 5;   // (32, 8)
    #pragma unroll
    for (int i = 0; i < 32; i += 8)
      tile[ty + i][tx] = src[(size_t)(k0 + ty + i) * 512 + n0 + tx];
    __syncthreads();
    short* dst = Wt + (size_t)z * 262144;
    #pragma unroll
    for (int i = 0; i < 32; i += 8)
      dst[(size_t)(n0 + ty + i) * 512 + k0 + tx] = (short)f2bf(tile[tx][ty + i] * wsc);
  }
}

// ---------------- GEMM A (QKV): C(8192x512) = xb @ W + bias, 128x128 tiles ----------------
// 768 blocks (XCD-swizzled), z in {0,1,2} -> Q row-major (scaled), K/V fragment-order
// Kept at m97 2-barrier structure: 4 blocks/CU -- implicit wave overlap already
// hides staging (guide m99/m100: explicit dbuf neutral at >=3 blocks/CU).
template <int MODE>
__global__ __launch_bounds__(256) void sa_gemm(const short* __restrict__ Abuf,
                                               const short* __restrict__ Wt,
                                               const float* __restrict__ bias0,
                                               const float* __restrict__ bias1,
                                               const float* __restrict__ bias2,
                                               short* __restrict__ Qb,
                                               short* __restrict__ Kb2,
                                               short* __restrict__ Vb2,
                                               float* __restrict__ outp) {
  __shared__ __align__(16) short A_lds[128 * 64];
  __shared__ __align__(16) short B_lds[128 * 64];
  const int tid = threadIdx.x, lane = tid & 63, wave = tid >> 6;
  const int dd0 = blockIdx.x;
  const int L = (MODE == 0) ? ((dd0 & 7) * 96 + (dd0 >> 3))
                            : ((dd0 & 7) * 32 + (dd0 >> 3));
  const int by = L & 3, bx = (L >> 2) & 63;
  const int z = (MODE == 0) ? (L >> 8) : 3;
  const int row0 = bx * 128, col0 = by * 128;
  const short* Bsrc = Wt + (size_t)z * 262144;   // [512 n][512 k]
  const int wr = wave >> 1, wc = wave & 1;

  f32x4 acc[4][4];
  const f32x4 zf = {0.f, 0.f, 0.f, 0.f};
  #pragma unroll
  for (int mi = 0; mi < 4; ++mi)
    #pragma unroll
    for (int ni = 0; ni < 4; ++ni) acc[mi][ni] = zf;

  for (int k0 = 0; k0 < 512; k0 += 64) {
    __syncthreads();
    #pragma unroll
    for (int j = 0; j < 4; ++j) {
      int chunk = j * 256 + wave * 64 + lane;   // 1024 chunks of 8 bf16
      int row = chunk >> 3;
      int cc = (chunk & 7) ^ (row & 7);
      gload_lds16(Abuf + (size_t)(row0 + row) * 512 + k0 + cc * 8,
                  &A_lds[(j * 256 + wave * 64) * 8]);
      gload_lds16(Bsrc + (size_t)(col0 + row) * 512 + k0 + cc * 8,
                  &B_lds[(j * 256 + wave * 64) * 8]);
    }
    __syncthreads();
    #pragma unroll
    for (int kk = 0; kk < 2; ++kk) {
      short8 af[4], bf[4];
      #pragma unroll
      for (int mi = 0; mi < 4; ++mi) {
        int r = wr * 64 + mi * 16 + (lane & 15);
        int cs = (kk * 4 + (lane >> 4)) ^ (r & 7);
        af[mi] = *(const short8*)&A_lds[r * 64 + cs * 8];
      }
      #pragma unroll
      for (int ni = 0; ni < 4; ++ni) {
        int r = wc * 64 + ni * 16 + (lane & 15);
        int cs = (kk * 4 + (lane >> 4)) ^ (r & 7);
        bf[ni] = *(const short8*)&B_lds[r * 64 + cs * 8];
      }
      #pragma unroll
      for (int mi = 0; mi < 4; ++mi)
        #pragma unroll
        for (int ni = 0; ni < 4; ++ni)
          acc[mi][ni] = mfma_bf16(af[mi], bf[ni], acc[mi][ni]);
    }
  }

  if (MODE == 0) {
    const float* bias = (z == 0) ? bias0 : (z == 1) ? bias1 : bias2;
    const float bscale = (z == 0) ? CF_ : 1.0f;
    #pragma unroll
    for (int ni = 0; ni < 4; ++ni) {
      int n = col0 + wc * 64 + ni * 16 + (lane & 15);
      float bsv = bias[n] * bscale;
      int hhd = n >> 6, dd = n & 63;
      #pragma unroll
      for (int mi = 0; mi < 4; ++mi) {
        int rg = row0 + wr * 64 + mi * 16 + ((lane >> 4) << 2);
        int bb = rg >> 11, ss = rg & 2047;
        size_t bhI = (size_t)(bb * NH_ + hhd);
        if (z == 0) {
          size_t base = bhI << 17;
          #pragma unroll
          for (int j = 0; j < 4; ++j)
            Qb[base + (size_t)(ss + j) * 64 + dd] = (short)f2bf(acc[mi][ni][j] + bsv);
        } else if (z == 1) {
          // K fragment granules: [bh][t][half*4+c][lane2=dh*32+lr][e], e along d
          int c = dd >> 4, dh = (dd >> 3) & 1, e = dd & 7;
          int t = ss >> 6, half = (ss >> 5) & 1, lr = ss & 31;
          size_t g = (bhI * 32 + t) * 4096 + (size_t)(half * 4 + c) * 512 + e;
          #pragma unroll
          for (int j = 0; j < 4; ++j)
            Kb2[g + (size_t)(dh * 32 + lr + j) * 8] = (short)f2bf(acc[mi][ni][j] + bsv);
        } else {
          // V fragment granules: [bh][t][kc*2+dhalf][lane2=kh*32+lr][e], e along kpos
          int dhalf = dd >> 5, lr = dd & 31;
          int t = ss >> 6, ks = ss & 63;
          int kc = ks >> 4, kh = (ks >> 3) & 1, e0 = ks & 7;
          size_t g = (bhI * 32 + t) * 4096 + (size_t)(kc * 2 + dhalf) * 512 +
                     (size_t)(kh * 32 + lr) * 8 + e0;
          short4v pk;
          #pragma unroll
          for (int j = 0; j < 4; ++j) pk[j] = (short)f2bf(acc[mi][ni][j] + bsv);
          *(short4v*)&Vb2[g] = pk;
        }
      }
    }
  } else {
    #pragma unroll
    for (int ni = 0; ni < 4; ++ni) {
      int n = col0 + wc * 64 + ni * 16 + (lane & 15);
      float bsv = bias0[n];
      #pragma unroll
      for (int mi = 0; mi < 4; ++mi) {
        int rg = row0 + wr * 64 + mi * 16 + ((lane >> 4) << 2);
        #pragma unroll
        for (int j = 0; j < 4; ++j)
          outp[(size_t)(rg + j) * 512 + n] = acc[mi][ni][j] + bsv;
      }
    }
  }
}

// ---------------- GEMM B (out-proj): 64x128 tiles, 512 blocks, DOUBLE-BUFFERED ----------------
// Round-15: gemmB runs at only 2 waves/SIMD -- no implicit cross-wave overlap
// to hide the hard vmcnt(0) drain of just-issued staging loads (unlike gemm0
// at 4 blocks/CU). Explicit dbuf: stage(t+1) issued BEFORE compute(t), the
// single vmcnt(0)+barrier per iter lands ~1000cy after issue (soft drain).
// LDS 48 KB.
__global__ __launch_bounds__(256) void sa_gemmB(const short* __restrict__ Abuf,
                                                const short* __restrict__ Wt,
                                                const float* __restrict__ bias,
                                                float* __restrict__ outp) {
  __shared__ __align__(16) short A_lds[2][64 * 64];    // 2 x 8 KB
  __shared__ __align__(16) short B_lds[2][128 * 64];   // 2 x 16 KB
  const int tid = threadIdx.x, lane = tid & 63, wave = tid >> 6;
  const int dd0 = blockIdx.x;                 // 512 = 8 * 64, bijective
  const int L = (dd0 & 7) * 64 + (dd0 >> 3);
  const int by = L & 3, bx = L >> 2;          // bx 0..127
  const int row0 = bx * 64, col0 = by * 128;
  const short* Bsrc = Wt + (size_t)3 * 262144;   // Wo^T [512 n][512 k]
  const int wr = wave >> 1, wc = wave & 1;

  f32x4 acc[2][4];
  const f32x4 zf = {0.f, 0.f, 0.f, 0.f};
  #pragma unroll
  for (int mi = 0; mi < 2; ++mi)
    #pragma unroll
    for (int ni = 0; ni < 4; ++ni) acc[mi][ni] = zf;

  auto STAGE = [&](int buf, int k0) {
    #pragma unroll
    for (int j = 0; j < 2; ++j) {   // A: 512 granules
      int chunk = j * 256 + tid;
      int row = chunk >> 3;
      int cc = (chunk & 7) ^ (row & 7);
      gload_lds16(Abuf + (size_t)(row0 + row) * 512 + k0 + cc * 8,
                  &A_lds[buf][(j * 256 + wave * 64) * 8]);
    }
    #pragma unroll
    for (int j = 0; j < 4; ++j) {   // B: 1024 granules
      int chunk = j * 256 + tid;
      int row = chunk >> 3;
      int cc = (chunk & 7) ^ (row & 7);
      gload_lds16(Bsrc + (size_t)(col0 + row) * 512 + k0 + cc * 8,
                  &B_lds[buf][(j * 256 + wave * 64) * 8]);
    }
  };

  STAGE(0, 0);
  asm volatile("s_waitcnt vmcnt(0)" ::: "memory");
  __builtin_amdgcn_s_barrier();

  for (int t = 0; t < 8; ++t) {
    const int buf = t & 1;
    if (t < 7) STAGE(buf ^ 1, (t + 1) * 64);   // overlaps compute below
    const short* Al = &A_lds[buf][0];
    const short* Bl = &B_lds[buf][0];
    #pragma unroll
    for (int kk = 0; kk < 2; ++kk) {
      short8 af[2], bf[4];
      #pragma unroll
      for (int mi = 0; mi < 2; ++mi) {
        int r = wr * 32 + mi * 16 + (lane & 15);
        int cs = (kk * 4 + (lane >> 4)) ^ (r & 7);
        af[mi] = *(const short8*)&Al[r * 64 + cs * 8];
      }
      #pragma unroll
      for (int ni = 0; ni < 4; ++ni) {
        int r = wc * 64 + ni * 16 + (lane & 15);
        int cs = (kk * 4 + (lane >> 4)) ^ (r & 7);
        bf[ni] = *(const short8*)&Bl[r * 64 + cs * 8];
      }
      #pragma unroll
      for (int mi = 0; mi < 2; ++mi)
        #pragma unroll
        for (int ni = 0; ni < 4; ++ni)
          acc[mi][ni] = mfma_bf16(af[mi], bf[ni], acc[mi][ni]);
    }
    // soft drain: stage(t+1) had the whole compute phase to land
    asm volatile("s_waitcnt vmcnt(0)" ::: "memory");
    __builtin_amdgcn_s_barrier();
  }

  #pragma unroll
  for (int ni = 0; ni < 4; ++ni) {
    int n = col0 + wc * 64 + ni * 16 + (lane & 15);
    float bsv = bias[n];
    #pragma unroll
    for (int mi = 0; mi < 2; ++mi) {
      int rg = row0 + wr * 32 + mi * 16 + ((lane >> 4) << 2);
      #pragma unroll
      for (int j = 0; j < 4; ++j)
        outp[(size_t)(rg + j) * 512 + n] = acc[mi][ni][j] + bsv;
    }
  }
}

// ---------------- kernel 4: flash attention (barrier-free, K/V direct from L2) ----------------
// 1-D grid 512 (XCD-swizzled), 512 threads = 4 q-groups x 2 k-segments.
// K/V L2-resident (XCD swizzle pins 4 MB per XCD); fragments loaded
// global->VGPR, zero main-loop barriers, waves free-run. VGPR 84 (natural --
// NO min-waves bound: 80-VGPR 6-wave cliff spills, measured rounds 7/11).
// Occupancy pinned at 4 waves/SIMD by VGPR halving (m69); MFMA 28% + VALU 38%
// at that occupancy -- structurally converged (effective ~700 TF, in line with
// the D=64 scaling of HK's 1480 TF D=128 reference).
__global__ __launch_bounds__(512) void sa_attn(const short* __restrict__ Qb,
                                               const short* __restrict__ Kb2,
                                               const short* __restrict__ Vb2,
                                               short* __restrict__ Ob) {
  __shared__ float Oxs[4][2048];   // 32 KB: seg-1 o partials
  __shared__ float Mls[4][32];     // seg-1 l partials
  const int tid = threadIdx.x, lane = tid & 63, wave = tid >> 6;
  const int seg = wave >> 2, wq = wave & 3;
  const int dd0 = blockIdx.x;                 // 512 = 8 * 64, bijective
  const int wg = (dd0 & 7) * 64 + (dd0 >> 3); // all 16 q-tiles of a (b,h) pair on one XCD
  const int qb = wg & 15, hb = (wg >> 4) & 7, b = wg >> 7;
  const size_t bh32 = ((size_t)(b * NH_ + hb)) * 32;
  const int q0w = qb * 128 + wq * 32;
  const int l31 = lane & 31, hh = lane >> 5, base32 = lane & 32;
  const int lo = lane * 8;
  const int sg16 = seg * 16;

  // Q frags (B-operand): q = q0w + l31, d = c*16 + hh*8 + {0..7}
  const size_t bhq = ((size_t)(b * NH_ + hb)) << 17;
  short8 qf[4];
  #pragma unroll
  for (int c = 0; c < 4; ++c)
    qf[c] = *(const short8*)&Qb[bhq + (size_t)(q0w + l31) * 64 + c * 16 + hh * 8];

  f32x16 o0 = {}, o1 = {};
  const f32x16 FZ = {};
  float lpart = 0.f;                       // per-lane partial row-sum

  const short* Kp = Kb2 + (bh32 + sg16) * 4096;
  const short* Vp = Vb2 + (bh32 + sg16) * 4096;

  // prologue: K(0), V(0) fragments into registers
  short8 kf[8], vf[8];
  #pragma unroll
  for (int c = 0; c < 8; ++c) kf[c] = *(const short8*)&Kp[c * 512 + lo];
  #pragma unroll
  for (int c = 0; c < 8; ++c) vf[c] = *(const short8*)&Vp[c * 512 + lo];

  for (int t = 0; t < 16; ++t) {
    // ---- QK(t): compiler waits kf here (counted vmcnt, V stays in flight)
    f32x16 s0, s1;
    s0 = mfma32(kf[0], qf[0], FZ);
    s1 = mfma32(kf[4], qf[0], FZ);
    #pragma unroll
    for (int c = 1; c < 4; ++c) {
      s0 = mfma32(kf[c], qf[c], s0);
      s1 = mfma32(kf[4 + c], qf[c], s1);
    }
    // ---- re-issue K(t+1) into kf (consumed above); lands during exp+PV
    if (t + 1 < 16) {
      const short* Kn = Kp + 4096;
      #pragma unroll
      for (int c = 0; c < 8; ++c) kf[c] = *(const short8*)&Kn[c * 512 + lo];
      Kp = Kn;
    }

    // ---- exp pass: P = exp2(s), lane-local partial sums ----
    float ps0 = 0.f, ps1 = 0.f, ps2 = 0.f, ps3 = 0.f;
    #pragma unroll
    for (int r = 0; r < 16; ++r) {
      float p0 = __builtin_amdgcn_exp2f(s0[r]);
      float p1 = __builtin_amdgcn_exp2f(s1[r]);
      s0[r] = p0; s1[r] = p1;
      if ((r & 3) == 0)      ps0 += p0 + p1;
      else if ((r & 3) == 1) ps1 += p0 + p1;
      else if ((r & 3) == 2) ps2 += p0 + p1;
      else                   ps3 += p0 + p1;
    }
    lpart += (ps0 + ps1) + (ps2 + ps3);

    // ---- PV(t): compiler waits vf here; pack fused per-kc ----
    __builtin_amdgcn_s_setprio(1);
    #pragma unroll
    for (int kc = 0; kc < 4; ++kc) {
      const f32x16& cs = (kc < 2) ? s0 : s1;
      const int e = (kc & 1) * 8;
      unsigned int w0 = packbf(cs[e],     cs[e + 1]);
      unsigned int w1 = packbf(cs[e + 2], cs[e + 3]);
      unsigned int w2 = packbf(cs[e + 4], cs[e + 5]);
      unsigned int w3 = packbf(cs[e + 6], cs[e + 7]);
      u32x2 p02 = pl32swap(w0, w2);
      u32x2 p13 = pl32swap(w1, w3);
      u32x4 paw = {p02[0], p13[0], p02[1], p13[1]};
      short8 pa = __builtin_bit_cast(short8, paw);
      o0 = mfma32(pa, vf[kc * 2], o0);
      o1 = mfma32(pa, vf[kc * 2 + 1], o1);
    }
    __builtin_amdgcn_s_setprio(0);

    // ---- re-issue V(t+1) into vf (consumed above); lands during QK(t+1)
    if (t + 1 < 16) {
      const short* Vn = Vp + 4096;
      #pragma unroll
      for (int c = 0; c < 8; ++c) vf[c] = *(const short8*)&Vn[c * 512 + lo];
      Vp = Vn;
    }
  }

  // ---- cross-half row sum (deferred from the loop) ----
  u32x2 lp = pl32swap(__builtin_bit_cast(unsigned int, lpart),
                      __builtin_bit_cast(unsigned int, lpart));
  float lrow = __builtin_bit_cast(float, lp[0]) + __builtin_bit_cast(float, lp[1]);

  // ---- combine the two k-segments (plain addition: shared m=0), write Ob ----
  if (seg == 1) {
    if (lane < 32) Mls[wq][lane] = lrow;
    #pragma unroll
    for (int r = 0; r < 16; ++r) {
      int qr = (r & 3) + 8 * (r >> 2) + 4 * hh;
      Oxs[wq][qr * 64 + l31]      = o0[r];
      Oxs[wq][qr * 64 + 32 + l31] = o1[r];
    }
  }
  __syncthreads();
  if (seg == 0) {
    float l1 = Mls[wq][l31];
    float inv = 1.f / (lrow + l1);
    #pragma unroll
    for (int r = 0; r < 16; ++r) {
      int qr = (r & 3) + 8 * (r >> 2) + 4 * hh;
      float I = __shfl(inv, base32 + qr);
      float v0 = (o0[r] + Oxs[wq][qr * 64 + l31]) * I;
      float v1 = (o1[r] + Oxs[wq][qr * 64 + 32 + l31]) * I;
      size_t rowb = ((size_t)(b * S_ + q0w + qr)) * 512 + hb * 64;
      Ob[rowb + l31]      = (short)f2bf(v0);
      Ob[rowb + 32 + l31] = (short)f2bf(v1);
    }
  }
}

// ---------------- launcher ----------------
extern "C" void kernel_launch(void* const* d_in, const int* in_sizes, int n_in,
                              void* d_out, int out_size, void* d_ws, size_t ws_size,
                              hipStream_t stream) {
  const float* x  = (const float*)d_in[0];
  const float* Wq = (const float*)d_in[1];
  const float* bq = (const float*)d_in[2];
  const float* Wk = (const float*)d_in[3];
  const float* bk = (const float*)d_in[4];
  const float* Wv = (const float*)d_in[5];
  const float* bv = (const float*)d_in[6];
  const float* Wo = (const float*)d_in[7];
  const float* bo = (const float*)d_in[8];
  float* out = (float*)d_out;

  short* ws = (short*)d_ws;
  short* xb  = ws;                  // 8192*512  = 4,194,304 shorts
  short* Wt  = ws + 4194304;        // 4*512*512 = 1,048,576
  short* Qb  = ws + 5242880;        // (B,H,S,D) = 4,194,304
  short* Kb2 = ws + 9437184;        // K fragment-order = 4,194,304
  short* Vb2 = ws + 13631488;       // V fragment-order = 4,194,304
  short* Ob  = ws + 17825792;       // (B*S, 512) = 4,194,304  (end: 44 MB)

  hipLaunchKernelGGL(sa_prep, dim3(3072), dim3(256), 0, stream,
                     x, xb, Wq, Wk, Wv, Wo, Wt);
  hipLaunchKernelGGL(sa_gemm<0>, dim3(768), dim3(256), 0, stream,
                     xb, Wt, bq, bk, bv, Qb, Kb2, Vb2, (float*)nullptr);
  hipLaunchKernelGGL(sa_attn, dim3(512), dim3(512), 0, stream, Qb, Kb2, Vb2, Ob);
  hipLaunchKernelGGL(sa_gemmB, dim3(512), dim3(256), 0, stream,
                     Ob, Wt, bo, out);
}

// Round 16
// 92.326 us; speedup vs baseline: 1.0118x; 1.0118x over previous
//
#include <hip/hip_runtime.h>
#include <stdint.h>

#define B_   4
#define S_   2048
#define IN_  512
#define HID_ 512
#define NH_  8
#define HD_  64
#define M_   (B_*S_)   // 8192
#define CF_  0.18033688011112042f   // log2(e)/8, folded into Wq/bq

typedef __attribute__((ext_vector_type(8)))  short  short8;
typedef __attribute__((ext_vector_type(4)))  short  short4v;
typedef __attribute__((ext_vector_type(4)))  float  f32x4;
typedef __attribute__((ext_vector_type(16))) float  f32x16;
typedef __attribute__((ext_vector_type(8)))  __bf16 bf16x8;
typedef __attribute__((ext_vector_type(2)))  __bf16 bf16x2;
typedef __attribute__((ext_vector_type(4)))  unsigned int u32x4;
typedef __attribute__((ext_vector_type(2)))  unsigned int u32x2;

// fp32 -> bf16 bits, round-to-nearest-even
__device__ __forceinline__ unsigned short f2bf(float f) {
  union { float f; unsigned u; } v; v.f = f;
  unsigned r = (v.u + 0x7fffu + ((v.u >> 16) & 1u)) >> 16;
  return (unsigned short)r;
}

// pack 2 f32 -> u32 of 2 bf16 (v_cvt_pk_bf16_f32)
__device__ __forceinline__ unsigned int packbf(float a, float b) {
  bf16x2 t; t[0] = (__bf16)a; t[1] = (__bf16)b;
  return __builtin_bit_cast(unsigned int, t);
}

// lane-half swap. r[0] = lanes<32: a(own) | lanes>=32: b(partner)
//                 r[1] = lanes<32: a(partner) | lanes>=32: b(own)
__device__ __forceinline__ u32x2 pl32swap(unsigned int a, unsigned int b) {
  return __builtin_amdgcn_permlane32_swap(a, b, false, false);
}

__device__ __forceinline__ f32x4 mfma_bf16(short8 a, short8 b, f32x4 c) {
  return __builtin_amdgcn_mfma_f32_16x16x32_bf16(
      __builtin_bit_cast(bf16x8, a), __builtin_bit_cast(bf16x8, b), c, 0, 0, 0);
}

__device__ __forceinline__ f32x16 mfma32(short8 a, short8 b, f32x16 c) {
  return __builtin_amdgcn_mfma_f32_32x32x16_bf16(
      __builtin_bit_cast(bf16x8, a), __builtin_bit_cast(bf16x8, b), c, 0, 0, 0);
}

// async global->LDS, 16B per lane; dst wave-uniform base (+lane*16 implicit)
__device__ __forceinline__ void gload_lds16(const void* g, void* l) {
  __builtin_amdgcn_global_load_lds(
      (__attribute__((address_space(1))) void*)g,
      (__attribute__((address_space(3))) void*)l, 16, 0, 0);
}

// ---------------- kernel 1: fused prep ----------------
// blocks [0,2048): x fp32 -> xb bf16.  blocks [2048,3072): W transpose+convert.
// Wq is pre-scaled by CF_ (log2e/8) so attention scores arrive in exp2 units.
__global__ __launch_bounds__(256) void sa_prep(const float* __restrict__ x,
                                               short* __restrict__ xb,
                                               const float* __restrict__ Wq,
                                               const float* __restrict__ Wk,
                                               const float* __restrict__ Wv,
                                               const float* __restrict__ Wo,
                                               short* __restrict__ Wt) {
  __shared__ float tile[32][33];
  const int bid = blockIdx.x, tid = threadIdx.x;
  if (bid < 2048) {
    int i = (bid * 256 + tid) * 8;
    const float4* p = (const float4*)&x[i];
    float4 a = p[0], b2 = p[1];
    short8 r;
    r[0] = (short)f2bf(a.x);  r[1] = (short)f2bf(a.y);
    r[2] = (short)f2bf(a.z);  r[3] = (short)f2bf(a.w);
    r[4] = (short)f2bf(b2.x); r[5] = (short)f2bf(b2.y);
    r[6] = (short)f2bf(b2.z); r[7] = (short)f2bf(b2.w);
    *(short8*)&xb[i] = r;
  } else {
    const int wb = bid - 2048;
    const int z = wb >> 8, rem = wb & 255;
    const float* src = (z == 0) ? Wq : (z == 1) ? Wk : (z == 2) ? Wv : Wo;
    const float wsc = (z == 0) ? CF_ : 1.0f;
    const int k0 = (rem >> 4) * 32, n0 = (rem & 15) * 32;
    const int tx = tid & 31, ty = tid >> 5;   // (32, 8)
    #pragma unroll
    for (int i = 0; i < 32; i += 8)
      tile[ty + i][tx] = src[(size_t)(k0 + ty + i) * 512 + n0 + tx];
    __syncthreads();
    short* dst = Wt + (size_t)z * 262144;
    #pragma unroll
    for (int i = 0; i < 32; i += 8)
      dst[(size_t)(n0 + ty + i) * 512 + k0 + tx] = (short)f2bf(tile[tx][ty + i] * wsc);
  }
}

// ---------------- GEMM A (QKV): C(8192x512) = xb @ W + bias, 128x128 tiles ----------------
// 768 blocks (XCD-swizzled), z in {0,1,2} -> Q row-major (scaled), K/V fragment-order
template <int MODE>
__global__ __launch_bounds__(256) void sa_gemm(const short* __restrict__ Abuf,
                                               const short* __restrict__ Wt,
                                               const float* __restrict__ bias0,
                                               const float* __restrict__ bias1,
                                               const float* __restrict__ bias2,
                                               short* __restrict__ Qb,
                                               short* __restrict__ Kb2,
                                               short* __restrict__ Vb2,
                                               float* __restrict__ outp) {
  __shared__ __align__(16) short A_lds[128 * 64];
  __shared__ __align__(16) short B_lds[128 * 64];
  const int tid = threadIdx.x, lane = tid & 63, wave = tid >> 6;
  const int dd0 = blockIdx.x;
  const int L = (MODE == 0) ? ((dd0 & 7) * 96 + (dd0 >> 3))
                            : ((dd0 & 7) * 32 + (dd0 >> 3));
  const int by = L & 3, bx = (L >> 2) & 63;
  const int z = (MODE == 0) ? (L >> 8) : 3;
  const int row0 = bx * 128, col0 = by * 128;
  const short* Bsrc = Wt + (size_t)z * 262144;   // [512 n][512 k]
  const int wr = wave >> 1, wc = wave & 1;

  f32x4 acc[4][4];
  const f32x4 zf = {0.f, 0.f, 0.f, 0.f};
  #pragma unroll
  for (int mi = 0; mi < 4; ++mi)
    #pragma unroll
    for (int ni = 0; ni < 4; ++ni) acc[mi][ni] = zf;

  for (int k0 = 0; k0 < 512; k0 += 64) {
    __syncthreads();
    #pragma unroll
    for (int j = 0; j < 4; ++j) {
      int chunk = j * 256 + wave * 64 + lane;   // 1024 chunks of 8 bf16
      int row = chunk >> 3;
      int cc = (chunk & 7) ^ (row & 7);
      gload_lds16(Abuf + (size_t)(row0 + row) * 512 + k0 + cc * 8,
                  &A_lds[(j * 256 + wave * 64) * 8]);
      gload_lds16(Bsrc + (size_t)(col0 + row) * 512 + k0 + cc * 8,
                  &B_lds[(j * 256 + wave * 64) * 8]);
    }
    __syncthreads();
    #pragma unroll
    for (int kk = 0; kk < 2; ++kk) {
      short8 af[4], bf[4];
      #pragma unroll
      for (int mi = 0; mi < 4; ++mi) {
        int r = wr * 64 + mi * 16 + (lane & 15);
        int cs = (kk * 4 + (lane >> 4)) ^ (r & 7);
        af[mi] = *(const short8*)&A_lds[r * 64 + cs * 8];
      }
      #pragma unroll
      for (int ni = 0; ni < 4; ++ni) {
        int r = wc * 64 + ni * 16 + (lane & 15);
        int cs = (kk * 4 + (lane >> 4)) ^ (r & 7);
        bf[ni] = *(const short8*)&B_lds[r * 64 + cs * 8];
      }
      #pragma unroll
      for (int mi = 0; mi < 4; ++mi)
        #pragma unroll
        for (int ni = 0; ni < 4; ++ni)
          acc[mi][ni] = mfma_bf16(af[mi], bf[ni], acc[mi][ni]);
    }
  }

  if (MODE == 0) {
    const float* bias = (z == 0) ? bias0 : (z == 1) ? bias1 : bias2;
    const float bscale = (z == 0) ? CF_ : 1.0f;
    #pragma unroll
    for (int ni = 0; ni < 4; ++ni) {
      int n = col0 + wc * 64 + ni * 16 + (lane & 15);
      float bsv = bias[n] * bscale;
      int hhd = n >> 6, dd = n & 63;
      #pragma unroll
      for (int mi = 0; mi < 4; ++mi) {
        int rg = row0 + wr * 64 + mi * 16 + ((lane >> 4) << 2);
        int bb = rg >> 11, ss = rg & 2047;
        size_t bhI = (size_t)(bb * NH_ + hhd);
        if (z == 0) {
          size_t base = bhI << 17;
          #pragma unroll
          for (int j = 0; j < 4; ++j)
            Qb[base + (size_t)(ss + j) * 64 + dd] = (short)f2bf(acc[mi][ni][j] + bsv);
        } else if (z == 1) {
          // K fragment granules: [bh][t][half*4+c][lane2=dh*32+lr][e], e along d
          int c = dd >> 4, dh = (dd >> 3) & 1, e = dd & 7;
          int t = ss >> 6, half = (ss >> 5) & 1, lr = ss & 31;
          size_t g = (bhI * 32 + t) * 4096 + (size_t)(half * 4 + c) * 512 + e;
          #pragma unroll
          for (int j = 0; j < 4; ++j)
            Kb2[g + (size_t)(dh * 32 + lr + j) * 8] = (short)f2bf(acc[mi][ni][j] + bsv);
        } else {
          // V fragment granules: [bh][t][kc*2+dhalf][lane2=kh*32+lr][e], e along kpos
          int dhalf = dd >> 5, lr = dd & 31;
          int t = ss >> 6, ks = ss & 63;
          int kc = ks >> 4, kh = (ks >> 3) & 1, e0 = ks & 7;
          size_t g = (bhI * 32 + t) * 4096 + (size_t)(kc * 2 + dhalf) * 512 +
                     (size_t)(kh * 32 + lr) * 8 + e0;
          short4v pk;
          #pragma unroll
          for (int j = 0; j < 4; ++j) pk[j] = (short)f2bf(acc[mi][ni][j] + bsv);
          *(short4v*)&Vb2[g] = pk;
        }
      }
    }
  } else {
    #pragma unroll
    for (int ni = 0; ni < 4; ++ni) {
      int n = col0 + wc * 64 + ni * 16 + (lane & 15);
      float bsv = bias0[n];
      #pragma unroll
      for (int mi = 0; mi < 4; ++mi) {
        int rg = row0 + wr * 64 + mi * 16 + ((lane >> 4) << 2);
        #pragma unroll
        for (int j = 0; j < 4; ++j)
          outp[(size_t)(rg + j) * 512 + n] = acc[mi][ni][j] + bsv;
      }
    }
  }
}

// ---------------- GEMM B (out-proj): 64x128 tiles, 512 blocks (round-14 form) ----------------
// Single-buffered: round-15's explicit dbuf was neutral-to-negative (92.46 ->
// 93.41 us) -- extra prologue + 2x LDS cut resident blocks. Reverted.
__global__ __launch_bounds__(256) void sa_gemmB(const short* __restrict__ Abuf,
                                                const short* __restrict__ Wt,
                                                const float* __restrict__ bias,
                                                float* __restrict__ outp) {
  __shared__ __align__(16) short A_lds[64 * 64];    // 8 KB
  __shared__ __align__(16) short B_lds[128 * 64];   // 16 KB
  const int tid = threadIdx.x, lane = tid & 63, wave = tid >> 6;
  const int dd0 = blockIdx.x;                 // 512 = 8 * 64, bijective
  const int L = (dd0 & 7) * 64 + (dd0 >> 3);
  const int by = L & 3, bx = L >> 2;          // bx 0..127
  const int row0 = bx * 64, col0 = by * 128;
  const short* Bsrc = Wt + (size_t)3 * 262144;   // Wo^T [512 n][512 k]
  const int wr = wave >> 1, wc = wave & 1;

  f32x4 acc[2][4];
  const f32x4 zf = {0.f, 0.f, 0.f, 0.f};
  #pragma unroll
  for (int mi = 0; mi < 2; ++mi)
    #pragma unroll
    for (int ni = 0; ni < 4; ++ni) acc[mi][ni] = zf;

  for (int k0 = 0; k0 < 512; k0 += 64) {
    __syncthreads();
    #pragma unroll
    for (int j = 0; j < 2; ++j) {   // A: 512 granules
      int chunk = j * 256 + tid;
      int row = chunk >> 3;
      int cc = (chunk & 7) ^ (row & 7);
      gload_lds16(Abuf + (size_t)(row0 + row) * 512 + k0 + cc * 8,
                  &A_lds[(j * 256 + wave * 64) * 8]);
    }
    #pragma unroll
    for (int j = 0; j < 4; ++j) {   // B: 1024 granules
      int chunk = j * 256 + tid;
      int row = chunk >> 3;
      int cc = (chunk & 7) ^ (row & 7);
      gload_lds16(Bsrc + (size_t)(col0 + row) * 512 + k0 + cc * 8,
                  &B_lds[(j * 256 + wave * 64) * 8]);
    }
    __syncthreads();
    #pragma unroll
    for (int kk = 0; kk < 2; ++kk) {
      short8 af[2], bf[4];
      #pragma unroll
      for (int mi = 0; mi < 2; ++mi) {
        int r = wr * 32 + mi * 16 + (lane & 15);
        int cs = (kk * 4 + (lane >> 4)) ^ (r & 7);
        af[mi] = *(const short8*)&A_lds[r * 64 + cs * 8];
      }
      #pragma unroll
      for (int ni = 0; ni < 4; ++ni) {
        int r = wc * 64 + ni * 16 + (lane & 15);
        int cs = (kk * 4 + (lane >> 4)) ^ (r & 7);
        bf[ni] = *(const short8*)&B_lds[r * 64 + cs * 8];
      }
      #pragma unroll
      for (int mi = 0; mi < 2; ++mi)
        #pragma unroll
        for (int ni = 0; ni < 4; ++ni)
          acc[mi][ni] = mfma_bf16(af[mi], bf[ni], acc[mi][ni]);
    }
  }

  #pragma unroll
  for (int ni = 0; ni < 4; ++ni) {
    int n = col0 + wc * 64 + ni * 16 + (lane & 15);
    float bsv = bias[n];
    #pragma unroll
    for (int mi = 0; mi < 2; ++mi) {
      int rg = row0 + wr * 32 + mi * 16 + ((lane >> 4) << 2);
      #pragma unroll
      for (int j = 0; j < 4; ++j)
        outp[(size_t)(rg + j) * 512 + n] = acc[mi][ni][j] + bsv;
    }
  }
}

// ---------------- kernel 4: flash attention (barrier-free, K/V direct from L2) ----------------
// 1-D grid 512 (XCD-swizzled), 512 threads = 4 q-groups x 2 k-segments.
// K/V L2-resident (XCD swizzle pins 4 MB per XCD); fragments loaded
// global->VGPR, zero main-loop barriers, waves free-run. VGPR 84 (natural --
// NO min-waves bound: 80-VGPR 6-wave cliff spills, measured rounds 7/11).
// Occupancy pinned at 4 waves/SIMD by VGPR halving (m69); MFMA 28% + VALU 38%
// at that occupancy -- structurally converged.
__global__ __launch_bounds__(512) void sa_attn(const short* __restrict__ Qb,
                                               const short* __restrict__ Kb2,
                                               const short* __restrict__ Vb2,
                                               short* __restrict__ Ob) {
  __shared__ float Oxs[4][2048];   // 32 KB: seg-1 o partials
  __shared__ float Mls[4][32];     // seg-1 l partials
  const int tid = threadIdx.x, lane = tid & 63, wave = tid >> 6;
  const int seg = wave >> 2, wq = wave & 3;
  const int dd0 = blockIdx.x;                 // 512 = 8 * 64, bijective
  const int wg = (dd0 & 7) * 64 + (dd0 >> 3); // all 16 q-tiles of a (b,h) pair on one XCD
  const int qb = wg & 15, hb = (wg >> 4) & 7, b = wg >> 7;
  const size_t bh32 = ((size_t)(b * NH_ + hb)) * 32;
  const int q0w = qb * 128 + wq * 32;
  const int l31 = lane & 31, hh = lane >> 5, base32 = lane & 32;
  const int lo = lane * 8;
  const int sg16 = seg * 16;

  // Q frags (B-operand): q = q0w + l31, d = c*16 + hh*8 + {0..7}
  const size_t bhq = ((size_t)(b * NH_ + hb)) << 17;
  short8 qf[4];
  #pragma unroll
  for (int c = 0; c < 4; ++c)
    qf[c] = *(const short8*)&Qb[bhq + (size_t)(q0w + l31) * 64 + c * 16 + hh * 8];

  f32x16 o0 = {}, o1 = {};
  const f32x16 FZ = {};
  float lpart = 0.f;                       // per-lane partial row-sum

  const short* Kp = Kb2 + (bh32 + sg16) * 4096;
  const short* Vp = Vb2 + (bh32 + sg16) * 4096;

  // prologue: K(0), V(0) fragments into registers
  short8 kf[8], vf[8];
  #pragma unroll
  for (int c = 0; c < 8; ++c) kf[c] = *(const short8*)&Kp[c * 512 + lo];
  #pragma unroll
  for (int c = 0; c < 8; ++c) vf[c] = *(const short8*)&Vp[c * 512 + lo];

  for (int t = 0; t < 16; ++t) {
    // ---- QK(t): compiler waits kf here (counted vmcnt, V stays in flight)
    f32x16 s0, s1;
    s0 = mfma32(kf[0], qf[0], FZ);
    s1 = mfma32(kf[4], qf[0], FZ);
    #pragma unroll
    for (int c = 1; c < 4; ++c) {
      s0 = mfma32(kf[c], qf[c], s0);
      s1 = mfma32(kf[4 + c], qf[c], s1);
    }
    // ---- re-issue K(t+1) into kf (consumed above); lands during exp+PV
    if (t + 1 < 16) {
      const short* Kn = Kp + 4096;
      #pragma unroll
      for (int c = 0; c < 8; ++c) kf[c] = *(const short8*)&Kn[c * 512 + lo];
      Kp = Kn;
    }

    // ---- exp pass: P = exp2(s), lane-local partial sums ----
    float ps0 = 0.f, ps1 = 0.f, ps2 = 0.f, ps3 = 0.f;
    #pragma unroll
    for (int r = 0; r < 16; ++r) {
      float p0 = __builtin_amdgcn_exp2f(s0[r]);
      float p1 = __builtin_amdgcn_exp2f(s1[r]);
      s0[r] = p0; s1[r] = p1;
      if ((r & 3) == 0)      ps0 += p0 + p1;
      else if ((r & 3) == 1) ps1 += p0 + p1;
      else if ((r & 3) == 2) ps2 += p0 + p1;
      else                   ps3 += p0 + p1;
    }
    lpart += (ps0 + ps1) + (ps2 + ps3);

    // ---- PV(t): compiler waits vf here; pack fused per-kc ----
    __builtin_amdgcn_s_setprio(1);
    #pragma unroll
    for (int kc = 0; kc < 4; ++kc) {
      const f32x16& cs = (kc < 2) ? s0 : s1;
      const int e = (kc & 1) * 8;
      unsigned int w0 = packbf(cs[e],     cs[e + 1]);
      unsigned int w1 = packbf(cs[e + 2], cs[e + 3]);
      unsigned int w2 = packbf(cs[e + 4], cs[e + 5]);
      unsigned int w3 = packbf(cs[e + 6], cs[e + 7]);
      u32x2 p02 = pl32swap(w0, w2);
      u32x2 p13 = pl32swap(w1, w3);
      u32x4 paw = {p02[0], p13[0], p02[1], p13[1]};
      short8 pa = __builtin_bit_cast(short8, paw);
      o0 = mfma32(pa, vf[kc * 2], o0);
      o1 = mfma32(pa, vf[kc * 2 + 1], o1);
    }
    __builtin_amdgcn_s_setprio(0);

    // ---- re-issue V(t+1) into vf (consumed above); lands during QK(t+1)
    if (t + 1 < 16) {
      const short* Vn = Vp + 4096;
      #pragma unroll
      for (int c = 0; c < 8; ++c) vf[c] = *(const short8*)&Vn[c * 512 + lo];
      Vp = Vn;
    }
  }

  // ---- cross-half row sum (deferred from the loop) ----
  u32x2 lp = pl32swap(__builtin_bit_cast(unsigned int, lpart),
                      __builtin_bit_cast(unsigned int, lpart));
  float lrow = __builtin_bit_cast(float, lp[0]) + __builtin_bit_cast(float, lp[1]);

  // ---- combine the two k-segments (plain addition: shared m=0), write Ob ----
  if (seg == 1) {
    if (lane < 32) Mls[wq][lane] = lrow;
    #pragma unroll
    for (int r = 0; r < 16; ++r) {
      int qr = (r & 3) + 8 * (r >> 2) + 4 * hh;
      Oxs[wq][qr * 64 + l31]      = o0[r];
      Oxs[wq][qr * 64 + 32 + l31] = o1[r];
    }
  }
  __syncthreads();
  if (seg == 0) {
    float l1 = Mls[wq][l31];
    float inv = 1.f / (lrow + l1);
    #pragma unroll
    for (int r = 0; r < 16; ++r) {
      int qr = (r & 3) + 8 * (r >> 2) + 4 * hh;
      float I = __shfl(inv, base32 + qr);
      float v0 = (o0[r] + Oxs[wq][qr * 64 + l31]) * I;
      float v1 = (o1[r] + Oxs[wq][qr * 64 + 32 + l31]) * I;
      size_t rowb = ((size_t)(b * S_ + q0w + qr)) * 512 + hb * 64;
      Ob[rowb + l31]      = (short)f2bf(v0);
      Ob[rowb + 32 + l31] = (short)f2bf(v1);
    }
  }
}

// ---------------- launcher ----------------
extern "C" void kernel_launch(void* const* d_in, const int* in_sizes, int n_in,
                              void* d_out, int out_size, void* d_ws, size_t ws_size,
                              hipStream_t stream) {
  const float* x  = (const float*)d_in[0];
  const float* Wq = (const float*)d_in[1];
  const float* bq = (const float*)d_in[2];
  const float* Wk = (const float*)d_in[3];
  const float* bk = (const float*)d_in[4];
  const float* Wv = (const float*)d_in[5];
  const float* bv = (const float*)d_in[6];
  const float* Wo = (const float*)d_in[7];
  const float* bo = (const float*)d_in[8];
  float* out = (float*)d_out;

  short* ws = (short*)d_ws;
  short* xb  = ws;                  // 8192*512  = 4,194,304 shorts
  short* Wt  = ws + 4194304;        // 4*512*512 = 1,048,576
  short* Qb  = ws + 5242880;        // (B,H,S,D) = 4,194,304
  short* Kb2 = ws + 9437184;        // K fragment-order = 4,194,304
  short* Vb2 = ws + 13631488;       // V fragment-order = 4,194,304
  short* Ob  = ws + 17825792;       // (B*S, 512) = 4,194,304  (end: 44 MB)

  hipLaunchKernelGGL(sa_prep, dim3(3072), dim3(256), 0, stream,
                     x, xb, Wq, Wk, Wv, Wo, Wt);
  hipLaunchKernelGGL(sa_gemm<0>, dim3(768), dim3(256), 0, stream,
                     xb, Wt, bq, bk, bv, Qb, Kb2, Vb2, (float*)nullptr);
  hipLaunchKernelGGL(sa_attn, dim3(512), dim3(512), 0, stream, Qb, Kb2, Vb2, Ob);
  hipLaunchKernelGGL(sa_gemmB, dim3(512), dim3(256), 0, stream,
                     Ob, Wt, bo, out);
}